// Round 5
// baseline (346.479 us; speedup 1.0000x reference)
//
#include <hip/hip_runtime.h>
#include <math.h>

#define NB 4
#define L 4096
#define D 64
#define QPB 64            // query rows per block (8 waves: 4 row-groups x 2 col-halves)
#define TCOLS 128         // K-tile columns
#define NT (L / TCOLS)    // 32 tiles

typedef __attribute__((ext_vector_type(8))) short short8;   // 8 bf16 = 4 VGPRs
typedef __attribute__((ext_vector_type(4))) float floatx4;
typedef unsigned int u32;

// fp32 -> (hi, lo) bf16 pair: hi = RNE(x), lo = RNE(x - hi) (exact residual).
static __device__ inline ushort2 f2bf2(float x) {
    unsigned int u = __builtin_bit_cast(unsigned int, x);
    unsigned int uh = u + (0x7FFFu + ((u >> 16) & 1u));
    unsigned short h = (unsigned short)(uh >> 16);
    float hf = __builtin_bit_cast(float, (unsigned int)h << 16);
    float r = x - hf;
    unsigned int v = __builtin_bit_cast(unsigned int, r);
    unsigned short l = (unsigned short)((v + (0x7FFFu + ((v >> 16) & 1u))) >> 16);
    ushort2 p; p.x = h; p.y = l; return p;
}

// async global->LDS, 16 B per lane: LDS dest = uniform base + lane*16.
static __device__ inline void dma16(const unsigned short* g, unsigned short* l) {
    __builtin_amdgcn_global_load_lds(
        (const __attribute__((address_space(1))) u32*)g,
        (__attribute__((address_space(3))) u32*)l, 16, 0, 0);
}

// ws layout (ushorts): qh[16384][64] | ql[16384][64] | kw[128 tiles][16384]
// kw tile = hi plane 8192 (chunk-major [cq 8][col 128][8 bf16]) + lo plane 8192.
#define WS_QL 1048576
#define WS_KW 2097152

// ---- pre-pass: convert Q,K fp32 -> bf16 hi/lo into d_ws (K in LDS tile order)
__global__ __launch_bounds__(256)
void convert_kernel(const float* __restrict__ qg, const float* __restrict__ kg,
                    unsigned short* __restrict__ ws) {
    unsigned int i = blockIdx.x * 256 + threadIdx.x;   // 524288 threads
    if (i < 262144) {                                  // Q: 262144 float4
        float4 qv = ((const float4*)qg)[i];
        ushort2 p0 = f2bf2(qv.x), p1 = f2bf2(qv.y), p2 = f2bf2(qv.z), p3 = f2bf2(qv.w);
        ushort4 h; h.x = p0.x; h.y = p1.x; h.z = p2.x; h.w = p3.x;
        ushort4 l; l.x = p0.y; l.y = p1.y; l.z = p2.y; l.w = p3.y;
        *(ushort4*)&ws[i * 4] = h;
        *(ushort4*)&ws[WS_QL + i * 4] = l;
    } else {                                           // K: 262144 float4
        unsigned int j = i - 262144;
        float4 kv = ((const float4*)kg)[j];
        ushort2 p0 = f2bf2(kv.x), p1 = f2bf2(kv.y), p2 = f2bf2(kv.z), p3 = f2bf2(kv.w);
        ushort4 h; h.x = p0.x; h.y = p1.x; h.z = p2.x; h.w = p3.x;
        ushort4 l; l.x = p0.y; l.y = p1.y; l.z = p2.y; l.w = p3.y;
        unsigned int bcol = j >> 4;                    // global K row (b*4096+col)
        unsigned int f4   = j & 15;
        unsigned int tile = bcol >> 7;                 // global tile id (b*32+t)
        unsigned int tcol = bcol & 127;
        unsigned int cq   = f4 >> 1, half = f4 & 1;
        unsigned int base = tile * 16384 + (cq * 128 + tcol) * 8 + half * 4;
        *(ushort4*)&ws[WS_KW + base] = h;
        *(ushort4*)&ws[WS_KW + base + 8192] = l;
    }
}

__global__ __launch_bounds__(512, 2)
void sparse_attn_kernel(const unsigned short* __restrict__ ws,
                        const float* __restrict__ vg,
                        float* __restrict__ outg) {
    __shared__ unsigned short skt[2][16384];   // double-buffered K tile (hi+lo), 64 KB
    __shared__ float smv[QPB][5];              // cross-wave merge scratch
    __shared__ int   smc[QPB][5];
    __shared__ float smz[QPB];

    const int tid  = threadIdx.x;
    const int lane = tid & 63;
    const int w    = tid >> 6;        // 0..7
    const int rg   = w & 3;           // row-group (16 rows each)
    const int ch   = w >> 2;          // column half
    const int c16  = lane & 15;
    const int quad = lane >> 4;

    // XCD swizzle: blocks with blockIdx%8==x share one batch's K/V (L2-resident)
    const int sblk  = (blockIdx.x & 7) * 32 + (blockIdx.x >> 3);
    const int qbase = sblk * QPB;
    const int b     = qbase >> 12;

    const unsigned short* qh = ws;
    const unsigned short* ql = ws + WS_QL;
    const unsigned short* kw = ws + WS_KW + (size_t)b * NT * 16384;

    const float* vb = vg + (size_t)b * L * D;
    float* attng = outg + (size_t)NB * L * D;
    float4* zrow = (float4*)(attng + (size_t)qbase * L);

    // ---- Q fragments (loop-invariant), straight from d_ws: A[m=c16][k=quad*8+j]
    const int qrow = qbase + rg * 16 + c16;
    const short8 a0h = *(const short8*)&qh[(size_t)qrow * 64 + quad * 8];
    const short8 a1h = *(const short8*)&qh[(size_t)qrow * 64 + 32 + quad * 8];
    const short8 a0l = *(const short8*)&ql[(size_t)qrow * 64 + quad * 8];
    const short8 a1l = *(const short8*)&ql[(size_t)qrow * 64 + 32 + quad * 8];

    // ---- DMA tile 0 into buf 0 (32 x 1KB issues; 4 per wave)
#pragma unroll
    for (int jj = 0; jj < 4; ++jj) {
        int idx = w * 4 + jj;
        dma16(kw + idx * 512 + lane * 8, &skt[0][idx * 512]);
    }
    __syncthreads();

    float Z[4] = {0.f, 0.f, 0.f, 0.f};
    float tv[4][5];
    int   tc[4][5];
#pragma unroll
    for (int r = 0; r < 4; ++r)
#pragma unroll
        for (int i = 0; i < 5; ++i) { tv[r][i] = -INFINITY; tc[r][i] = -1; }

    for (int g = 0; g < NT; ++g) {
        // DMA next tile into the other buffer (completion enforced by the
        // end-of-iteration barrier's vmcnt drain).
        if (g + 1 < NT) {
#pragma unroll
            for (int jj = 0; jj < 4; ++jj) {
                int idx = w * 4 + jj;
                dma16(kw + (g + 1) * 16384 + idx * 512 + lane * 8,
                      &skt[(g + 1) & 1][idx * 512]);
            }
        }

        const unsigned short* kbh = skt[g & 1];
        const unsigned short* kbl = skt[g & 1] + 8192;

        // ---- this wave's column half: 4 of 8 col-groups
#pragma unroll
        for (int j = 0; j < 4; ++j) {
            const int cg = ch * 4 + j;
            const int cb = cg * 16 + c16;
            short8 b0h = *(const short8*)&kbh[((quad)     * 128 + cb) * 8];
            short8 b1h = *(const short8*)&kbh[((4 + quad) * 128 + cb) * 8];
            short8 b0l = *(const short8*)&kbl[((quad)     * 128 + cb) * 8];
            short8 b1l = *(const short8*)&kbl[((4 + quad) * 128 + cb) * 8];
            floatx4 acc = {0.f, 0.f, 0.f, 0.f};
            acc = __builtin_amdgcn_mfma_f32_16x16x32_bf16(a0h, b0h, acc, 0, 0, 0);
            acc = __builtin_amdgcn_mfma_f32_16x16x32_bf16(a1h, b1h, acc, 0, 0, 0);
            acc = __builtin_amdgcn_mfma_f32_16x16x32_bf16(a0l, b0h, acc, 0, 0, 0);
            acc = __builtin_amdgcn_mfma_f32_16x16x32_bf16(a1l, b1h, acc, 0, 0, 0);
            acc = __builtin_amdgcn_mfma_f32_16x16x32_bf16(a0h, b0l, acc, 0, 0, 0);
            acc = __builtin_amdgcn_mfma_f32_16x16x32_bf16(a1h, b1l, acc, 0, 0, 0);
            const int col = g * TCOLS + cb;
#pragma unroll
            for (int r = 0; r < 4; ++r) {
                float s = acc[r] * 0.125f;          // / TEMPERATURE
                Z[r] += __expf(s);
                bool q0 = s > tv[r][0];
                bool q1 = s > tv[r][1];
                bool q2 = s > tv[r][2];
                bool q3 = s > tv[r][3];
                bool q4 = s > tv[r][4];
                tv[r][4] = q4 ? (q3 ? tv[r][3] : s)   : tv[r][4];
                tc[r][4] = q4 ? (q3 ? tc[r][3] : col) : tc[r][4];
                tv[r][3] = q3 ? (q2 ? tv[r][2] : s)   : tv[r][3];
                tc[r][3] = q3 ? (q2 ? tc[r][2] : col) : tc[r][3];
                tv[r][2] = q2 ? (q1 ? tv[r][1] : s)   : tv[r][2];
                tc[r][2] = q2 ? (q1 ? tc[r][1] : col) : tc[r][2];
                tv[r][1] = q1 ? (q0 ? tv[r][0] : s)   : tv[r][1];
                tc[r][1] = q1 ? (q0 ? tc[r][0] : col) : tc[r][1];
                tv[r][0] = q0 ? s   : tv[r][0];
                tc[r][0] = q0 ? col : tc[r][0];
            }
        }

        // ---- zero-fill slice of this block's 64 dense attn rows (overlaps)
        float4 zv = make_float4(0.f, 0.f, 0.f, 0.f);
#pragma unroll
        for (int jj = 0; jj < 4; ++jj)
            zrow[(size_t)g * 2048 + jj * 512 + tid] = zv;

        __syncthreads();   // DMA(g+1) done; all waves finished reading buf g
    }

    // ---- epilogue stage 1: quad merge (16 lanes share each row); col-half 1
    // waves deposit their per-row top-5 + Z into LDS.
    float gv[4][5]; int gc[4][5]; float zz[4];
#pragma unroll
    for (int r = 0; r < 4; ++r) {
        float z = Z[r];
        z += __shfl_xor(z, 1, 64);
        z += __shfl_xor(z, 2, 64);
        z += __shfl_xor(z, 4, 64);
        z += __shfl_xor(z, 8, 64);
        zz[r] = z;
        const int rowl = rg * 16 + quad * 4 + r;
#pragma unroll
        for (int k5 = 0; k5 < 5; ++k5) {
            float cv = tv[r][0]; int cc = tc[r][0];
#pragma unroll
            for (int m = 8; m >= 1; m >>= 1) {
                float ov = __shfl_xor(cv, m, 64);
                int   oc = __shfl_xor(cc, m, 64);
                if (ov > cv || (ov == cv && oc < cc)) { cv = ov; cc = oc; }
            }
            gv[r][k5] = cv; gc[r][k5] = cc;
            if (ch == 1 && c16 == k5) { smv[rowl][k5] = cv; smc[rowl][k5] = cc; }
            if (tc[r][0] == cc) {                   // unique owner pops
                tv[r][0] = tv[r][1]; tc[r][0] = tc[r][1];
                tv[r][1] = tv[r][2]; tc[r][1] = tc[r][2];
                tv[r][2] = tv[r][3]; tc[r][2] = tc[r][3];
                tv[r][3] = tv[r][4]; tc[r][3] = tc[r][4];
                tv[r][4] = -INFINITY; tc[r][4] = -1;
            }
        }
        if (ch == 1 && c16 == 5) smz[rowl] = z;
    }
    __syncthreads();

    // ---- epilogue stage 2: col-half 0 waves merge the foreign half, sparsify,
    // and emit out + attn scatter.
    if (ch == 0) {
#pragma unroll
        for (int r = 0; r < 4; ++r) {
            const int rowl = rg * 16 + quad * 4 + r;
            float z = zz[r] + smz[rowl];
#pragma unroll
            for (int f = 0; f < 5; ++f) {
                float fv = smv[rowl][f];
                int   fc = smc[rowl][f];
                bool q0 = fv > gv[r][0];
                bool q1 = fv > gv[r][1];
                bool q2 = fv > gv[r][2];
                bool q3 = fv > gv[r][3];
                bool q4 = fv > gv[r][4];
                gv[r][4] = q4 ? (q3 ? gv[r][3] : fv) : gv[r][4];
                gc[r][4] = q4 ? (q3 ? gc[r][3] : fc) : gc[r][4];
                gv[r][3] = q3 ? (q2 ? gv[r][2] : fv) : gv[r][3];
                gc[r][3] = q3 ? (q2 ? gc[r][2] : fc) : gc[r][3];
                gv[r][2] = q2 ? (q1 ? gv[r][1] : fv) : gv[r][2];
                gc[r][2] = q2 ? (q1 ? gc[r][1] : fc) : gc[r][2];
                gv[r][1] = q1 ? (q0 ? gv[r][0] : fv) : gv[r][1];
                gc[r][1] = q1 ? (q0 ? gc[r][0] : fc) : gc[r][1];
                gv[r][0] = q0 ? fv : gv[r][0];
                gc[r][0] = q0 ? fc : gc[r][0];
            }

            float invz = 1.0f / z;
            float e0 = __expf(gv[r][0]) * invz;
            float e1 = __expf(gv[r][1]) * invz;
            float e2 = __expf(gv[r][2]) * invz;
            float e3 = __expf(gv[r][3]) * invz;
            float e4 = __expf(gv[r][4]) * invz;
            float delta = e4 + 1e-7f;
            float w0 = fmaxf(e0 - delta, 0.f);
            float w1 = fmaxf(e1 - delta, 0.f);
            float w2 = fmaxf(e2 - delta, 0.f);
            float w3 = fmaxf(e3 - delta, 0.f);
            float inv = 1.0f / (w0 + w1 + w2 + w3 + 1e-7f);
            w0 *= inv; w1 *= inv; w2 *= inv; w3 *= inv;

            const int rowabs = qbase + rowl;

            const float4 v0 = *(const float4*)(vb + (size_t)gc[r][0] * D + c16 * 4);
            const float4 v1 = *(const float4*)(vb + (size_t)gc[r][1] * D + c16 * 4);
            const float4 v2 = *(const float4*)(vb + (size_t)gc[r][2] * D + c16 * 4);
            const float4 v3 = *(const float4*)(vb + (size_t)gc[r][3] * D + c16 * 4);
            float4 o;
            o.x = w0 * v0.x + w1 * v1.x + w2 * v2.x + w3 * v3.x;
            o.y = w0 * v0.y + w1 * v1.y + w2 * v2.y + w3 * v3.y;
            o.z = w0 * v0.z + w1 * v1.z + w2 * v2.z + w3 * v3.z;
            o.w = w0 * v0.w + w1 * v1.w + w2 * v2.w + w3 * v3.w;
            *(float4*)(outg + (size_t)rowabs * D + c16 * 4) = o;

            // scatter <=4 nonzeros into the (zeroed) dense attn row
            if (c16 < 4) {
                float wv = c16 == 0 ? w0 : c16 == 1 ? w1 : c16 == 2 ? w2 : w3;
                int   cs = c16 == 0 ? gc[r][0] : c16 == 1 ? gc[r][1]
                         : c16 == 2 ? gc[r][2] : gc[r][3];
                attng[(size_t)rowabs * L + cs] = wv;
            }
        }
    }
}

extern "C" void kernel_launch(void* const* d_in, const int* in_sizes, int n_in,
                              void* d_out, int out_size, void* d_ws, size_t ws_size,
                              hipStream_t stream) {
    const float* q = (const float*)d_in[0];
    const float* k = (const float*)d_in[1];
    const float* v = (const float*)d_in[2];
    float* out = (float*)d_out;
    unsigned short* ws = (unsigned short*)d_ws;

    // 1) convert Q,K fp32 -> bf16 hi/lo into d_ws (K in LDS tile order)
    convert_kernel<<<2048, 256, 0, stream>>>(q, k, ws);

    // 2) fused sparse-attention kernel: 64 rows per 512-thread block
    dim3 grid(NB * L / QPB);                       // 256 blocks, 8 waves each
    sparse_attn_kernel<<<grid, 512, 0, stream>>>(ws, v, out);
}

// Round 6
// 334.851 us; speedup vs baseline: 1.0347x; 1.0347x over previous
//
#include <hip/hip_runtime.h>
#include <math.h>

#define NB 4
#define L 4096
#define D 64
// ws layout (ushorts): qh[16384][64] | ql[16384][64] | K: per batch
// [plane hi/lo][cq 8][col 4096][8 bf16]  (batch stride 524288, plane 262144)
#define WS_QL 1048576
#define WS_K  2097152
#define KBS   524288
#define KPL   262144
// Q pre-scale: 1/TEMPERATURE * log2(e)  -> scores in log2 units (monotone)
#define QSCALE 0.1803368801111243f

typedef __attribute__((ext_vector_type(8))) short short8;   // 8 bf16 = 4 VGPRs
typedef __attribute__((ext_vector_type(4))) float floatx4;

// fp32 -> (hi, lo) bf16 pair: hi = RNE(x), lo = RNE(x - hi) (exact residual).
static __device__ inline ushort2 f2bf2(float x) {
    unsigned int u = __builtin_bit_cast(unsigned int, x);
    unsigned int uh = u + (0x7FFFu + ((u >> 16) & 1u));
    unsigned short h = (unsigned short)(uh >> 16);
    float hf = __builtin_bit_cast(float, (unsigned int)h << 16);
    float r = x - hf;
    unsigned int v = __builtin_bit_cast(unsigned int, r);
    unsigned short l = (unsigned short)((v + (0x7FFFu + ((v >> 16) & 1u))) >> 16);
    ushort2 p; p.x = h; p.y = l; return p;
}

// ---- pre-pass: Q (scaled) and K fp32 -> bf16 hi/lo planes in d_ws
__global__ __launch_bounds__(256)
void convert_kernel(const float* __restrict__ qg, const float* __restrict__ kg,
                    unsigned short* __restrict__ ws) {
    unsigned int i = blockIdx.x * 256 + threadIdx.x;       // 524288 threads
    if (i < 262144) {                                      // Q: 262144 float4
        float4 qv = ((const float4*)qg)[i];
        ushort2 p0 = f2bf2(qv.x * QSCALE), p1 = f2bf2(qv.y * QSCALE),
                p2 = f2bf2(qv.z * QSCALE), p3 = f2bf2(qv.w * QSCALE);
        ushort4 h; h.x = p0.x; h.y = p1.x; h.z = p2.x; h.w = p3.x;
        ushort4 l; l.x = p0.y; l.y = p1.y; l.z = p2.y; l.w = p3.y;
        *(ushort4*)&ws[i * 4] = h;
        *(ushort4*)&ws[WS_QL + i * 4] = l;
    } else {                                               // K: 262144 float4
        unsigned int j = i - 262144;
        float4 kv = ((const float4*)kg)[j];
        ushort2 p0 = f2bf2(kv.x), p1 = f2bf2(kv.y), p2 = f2bf2(kv.z), p3 = f2bf2(kv.w);
        ushort4 h; h.x = p0.x; h.y = p1.x; h.z = p2.x; h.w = p3.x;
        ushort4 l; l.x = p0.y; l.y = p1.y; l.z = p2.y; l.w = p3.y;
        unsigned int bcol = j >> 4;                        // b*4096 + col
        unsigned int f4   = j & 15;
        unsigned int b    = bcol >> 12, col = bcol & 4095;
        unsigned int cq   = f4 >> 1, half = f4 & 1;
        size_t base = WS_K + (size_t)b * KBS + ((size_t)cq * 4096 + col) * 8 + half * 4;
        *(ushort4*)&ws[base] = h;
        *(ushort4*)&ws[base + KPL] = l;
    }
}

#define SENT 0x7FFFFFFF   // sentinel col: loses all lowest-col tie-breaks

__global__ __launch_bounds__(256, 4)
void sparse_attn_kernel(const unsigned short* __restrict__ ws,
                        const float* __restrict__ vg,
                        float* __restrict__ outg) {
    __shared__ float smv[3][16][5];     // foreign-wave top-5 values (slot4 = 5th val)
    __shared__ int   smc[3][16][4];     // foreign-wave top-4 cols

    const int tid  = threadIdx.x;
    const int lane = tid & 63;
    const int wid  = tid >> 6;          // column quarter 0..3
    const int c16  = lane & 15;
    const int quad = lane >> 4;

    // XCD swizzle: consecutive sblk on one XCD -> each XCD works one batch's
    // K/V (K bf16 1 MB/batch, L2-resident).
    const int sblk  = (blockIdx.x & 7) * 128 + (blockIdx.x >> 3);
    const int qbase = sblk * 16;        // 16 rows per block (shared by 4 waves)
    const int b     = qbase >> 12;

    const unsigned short* qh   = ws;
    const unsigned short* ql   = ws + WS_QL;
    const unsigned short* kbat = ws + WS_K + (size_t)b * KBS;
    const float* vb = vg + (size_t)b * L * D;
    float* attng = outg + (size_t)NB * L * D;

    // ---- Q fragments (loop-invariant): A[m=c16][k=quad*8+j], two K-steps
    const int qrow = qbase + c16;
    const short8 a0h = *(const short8*)&qh[(size_t)qrow * 64 + quad * 8];
    const short8 a1h = *(const short8*)&qh[(size_t)qrow * 64 + 32 + quad * 8];
    const short8 a0l = *(const short8*)&ql[(size_t)qrow * 64 + quad * 8];
    const short8 a1l = *(const short8*)&ql[(size_t)qrow * 64 + 32 + quad * 8];

    float tv[4][5];
    int   tc[4][4];                     // no col for slot 4 (never needed)
#pragma unroll
    for (int r = 0; r < 4; ++r) {
#pragma unroll
        for (int i = 0; i < 5; ++i) tv[r][i] = -INFINITY;
#pragma unroll
        for (int i = 0; i < 4; ++i) tc[r][i] = SENT;
    }

    // Per-wave column quarter; K fragment base pointers (b128, coalesced).
    const int colq = wid * 1024;
    const unsigned short* bp0 = kbat + ((size_t)(quad)     * 4096 + colq + c16) * 8;
    const unsigned short* bp1 = kbat + ((size_t)(4 + quad) * 4096 + colq + c16) * 8;
    const float4 zv = make_float4(0.f, 0.f, 0.f, 0.f);

    // ---- barrier-free hot loop: 64 groups of 16 columns
#pragma unroll 4
    for (int cg = 0; cg < 64; ++cg) {
        const int off = cg * 128;                   // 16 cols * 8 ushorts
        short8 b0h = *(const short8*)(bp0 + off);
        short8 b1h = *(const short8*)(bp1 + off);
        short8 b0l = *(const short8*)(bp0 + KPL + off);
        short8 b1l = *(const short8*)(bp1 + KPL + off);
        floatx4 acc = {0.f, 0.f, 0.f, 0.f};
        acc = __builtin_amdgcn_mfma_f32_16x16x32_bf16(a0h, b0h, acc, 0, 0, 0);
        acc = __builtin_amdgcn_mfma_f32_16x16x32_bf16(a1h, b1h, acc, 0, 0, 0);
        acc = __builtin_amdgcn_mfma_f32_16x16x32_bf16(a0l, b0h, acc, 0, 0, 0);
        acc = __builtin_amdgcn_mfma_f32_16x16x32_bf16(a1l, b1h, acc, 0, 0, 0);
        acc = __builtin_amdgcn_mfma_f32_16x16x32_bf16(a0h, b0l, acc, 0, 0, 0);
        acc = __builtin_amdgcn_mfma_f32_16x16x32_bf16(a1h, b1l, acc, 0, 0, 0);

        // zero-fill one float4 of this block's dense attn region (overlaps)
        {
            int idx = cg * 64 + lane;               // [0, 4096)
            *(float4*)&attng[(size_t)(qbase + (idx >> 8)) * L + colq + (idx & 255) * 4] = zv;
        }

        const int col = colq + cg * 16 + c16;
#pragma unroll
        for (int r = 0; r < 4; ++r) {
            float s = acc[r];                       // pre-scaled score (log2 units)
            bool q0 = s > tv[r][0];
            bool q1 = s > tv[r][1];
            bool q2 = s > tv[r][2];
            bool q3 = s > tv[r][3];
            bool q4 = s > tv[r][4];
            tv[r][4] = q4 ? (q3 ? tv[r][3] : s)   : tv[r][4];
            tv[r][3] = q3 ? (q2 ? tv[r][2] : s)   : tv[r][3];
            tc[r][3] = q3 ? (q2 ? tc[r][2] : col) : tc[r][3];
            tv[r][2] = q2 ? (q1 ? tv[r][1] : s)   : tv[r][2];
            tc[r][2] = q2 ? (q1 ? tc[r][1] : col) : tc[r][2];
            tv[r][1] = q1 ? (q0 ? tv[r][0] : s)   : tv[r][1];
            tc[r][1] = q1 ? (q0 ? tc[r][0] : col) : tc[r][1];
            tv[r][0] = q0 ? s   : tv[r][0];
            tc[r][0] = q0 ? col : tc[r][0];
        }
    }

    // ---- stage A: merge across the 16 lanes of each quad (rows quad*4+r)
    float gv[4][5]; int gc[4][4];
#pragma unroll
    for (int r = 0; r < 4; ++r) {
#pragma unroll
        for (int k5 = 0; k5 < 4; ++k5) {            // top-4 with cols (pop rounds)
            float cv = tv[r][0]; int cc = tc[r][0];
#pragma unroll
            for (int m = 8; m >= 1; m >>= 1) {
                float ov = __shfl_xor(cv, m, 64);
                int   oc = __shfl_xor(cc, m, 64);
                if (ov > cv || (ov == cv && oc < cc)) { cv = ov; cc = oc; }
            }
            gv[r][k5] = cv; gc[r][k5] = cc;
            if (tc[r][0] == cc && tv[r][0] == cv) { // unique owner pops
                tv[r][0] = tv[r][1]; tc[r][0] = tc[r][1];
                tv[r][1] = tv[r][2]; tc[r][1] = tc[r][2];
                tv[r][2] = tv[r][3]; tc[r][2] = tc[r][3];
                tv[r][3] = tv[r][4]; tc[r][3] = SENT;
                tv[r][4] = -INFINITY;
            }
        }
        float fv = tv[r][0];                        // 5th: value-only max
#pragma unroll
        for (int m = 8; m >= 1; m >>= 1) fv = fmaxf(fv, __shfl_xor(fv, m, 64));
        gv[r][4] = fv;
    }

    // ---- stage B: waves 1-3 deposit per-row records
    if (wid > 0) {
#pragma unroll
        for (int r = 0; r < 4; ++r) {
            const int rowl = quad * 4 + r;
            if (c16 < 4) {
                smv[wid - 1][rowl][c16] = gv[r][c16];
                smc[wid - 1][rowl][c16] = gc[r][c16];
            } else if (c16 == 4) {
                smv[wid - 1][rowl][4] = gv[r][4];
            }
        }
    }
    __syncthreads();    // also drains all zero-fill stores (vmcnt(0) pre-barrier)

    // ---- stage C: wave 0 merges foreign quarters, sparsifies, emits
    if (wid == 0) {
#pragma unroll
        for (int r = 0; r < 4; ++r) {
            const int rowl = quad * 4 + r;
            float lv[5]; int lc[4];
#pragma unroll
            for (int i = 0; i < 5; ++i) lv[i] = gv[r][i];
#pragma unroll
            for (int i = 0; i < 4; ++i) lc[i] = gc[r][i];

#pragma unroll
            for (int f = 0; f < 3; ++f) {
#pragma unroll
                for (int s5 = 0; s5 < 4; ++s5) {    // foreign top-4 (with col)
                    float v = smv[f][rowl][s5];
                    int   c = smc[f][rowl][s5];
                    bool q0 = v > lv[0];
                    bool q1 = v > lv[1];
                    bool q2 = v > lv[2];
                    bool q3 = v > lv[3];
                    bool q4 = v > lv[4];
                    lv[4] = q4 ? (q3 ? lv[3] : v) : lv[4];
                    lv[3] = q3 ? (q2 ? lv[2] : v) : lv[3];
                    lc[3] = q3 ? (q2 ? lc[2] : c) : lc[3];
                    lv[2] = q2 ? (q1 ? lv[1] : v) : lv[2];
                    lc[2] = q2 ? (q1 ? lc[1] : c) : lc[2];
                    lv[1] = q1 ? (q0 ? lv[0] : v) : lv[1];
                    lc[1] = q1 ? (q0 ? lc[0] : c) : lc[1];
                    lv[0] = q0 ? v : lv[0];
                    lc[0] = q0 ? c : lc[0];
                }
                {                                    // foreign 5th: value-only
                    float v = smv[f][rowl][4];
                    bool q0 = v > lv[0];
                    bool q1 = v > lv[1];
                    bool q2 = v > lv[2];
                    bool q3 = v > lv[3];
                    bool q4 = v > lv[4];
                    lv[4] = q4 ? (q3 ? lv[3] : v) : lv[4];
                    lv[3] = q3 ? (q2 ? lv[2] : v) : lv[3];
                    lv[2] = q2 ? (q1 ? lv[1] : v) : lv[2];
                    lv[1] = q1 ? (q0 ? lv[0] : v) : lv[1];
                    lv[0] = q0 ? v : lv[0];
                }
            }

            // sparsify, Z-free: w_i ∝ 2^(s_i - s_5) - 1  (exact ratio; the
            // reference's eps terms contribute <= ~1e-3 relative — see notes)
            float u0 = exp2f(lv[0] - lv[4]) - 1.0f;
            float u1 = exp2f(lv[1] - lv[4]) - 1.0f;
            float u2 = exp2f(lv[2] - lv[4]) - 1.0f;
            float u3 = exp2f(lv[3] - lv[4]) - 1.0f;
            float inv = 1.0f / (u0 + u1 + u2 + u3 + 1e-30f);
            float w0 = u0 * inv, w1 = u1 * inv, w2 = u2 * inv, w3 = u3 * inv;

            const int rowabs = qbase + rowl;

            // V gather (clamped for sentinel cols, whose weight is 0)
            unsigned int i0 = min((unsigned)lc[0], 4095u);
            unsigned int i1 = min((unsigned)lc[1], 4095u);
            unsigned int i2 = min((unsigned)lc[2], 4095u);
            unsigned int i3 = min((unsigned)lc[3], 4095u);
            const float4 v0 = *(const float4*)(vb + (size_t)i0 * D + c16 * 4);
            const float4 v1 = *(const float4*)(vb + (size_t)i1 * D + c16 * 4);
            const float4 v2 = *(const float4*)(vb + (size_t)i2 * D + c16 * 4);
            const float4 v3 = *(const float4*)(vb + (size_t)i3 * D + c16 * 4);
            float4 o;
            o.x = w0 * v0.x + w1 * v1.x + w2 * v2.x + w3 * v3.x;
            o.y = w0 * v0.y + w1 * v1.y + w2 * v2.y + w3 * v3.y;
            o.z = w0 * v0.z + w1 * v1.z + w2 * v2.z + w3 * v3.z;
            o.w = w0 * v0.w + w1 * v1.w + w2 * v2.w + w3 * v3.w;
            *(float4*)(outg + (size_t)rowabs * D + c16 * 4) = o;

            // scatter <=4 nonzeros into the (zeroed) dense attn row
            if (c16 < 4) {
                float wv = c16 == 0 ? w0 : c16 == 1 ? w1 : c16 == 2 ? w2 : w3;
                int   cs = c16 == 0 ? lc[0] : c16 == 1 ? lc[1]
                         : c16 == 2 ? lc[2] : lc[3];
                if ((unsigned)cs < 4096u && wv > 0.f)
                    attng[(size_t)rowabs * L + cs] = wv;
            }
        }
    }
}

extern "C" void kernel_launch(void* const* d_in, const int* in_sizes, int n_in,
                              void* d_out, int out_size, void* d_ws, size_t ws_size,
                              hipStream_t stream) {
    const float* q = (const float*)d_in[0];
    const float* k = (const float*)d_in[1];
    const float* v = (const float*)d_in[2];
    float* out = (float*)d_out;
    unsigned short* ws = (unsigned short*)d_ws;

    // 1) convert Q (pre-scaled) and K fp32 -> bf16 hi/lo planes in d_ws
    convert_kernel<<<2048, 256, 0, stream>>>(q, k, ws);

    // 2) barrier-free sparse attention: 16 rows x 4 col-quarter waves / block
    sparse_attn_kernel<<<1024, 256, 0, stream>>>(ws, v, out);
}